// Round 11
// baseline (363.300 us; speedup 1.0000x reference)
//
#include <hip/hip_runtime.h>
#include <math.h>

// ---------------- problem constants ----------------
#define B_    64
#define S_    512
#define HID_  256
#define NH_   4
#define DH_   64
#define BH_   (B_*NH_)            // 256 head-batches
#define BS_   (B_*S_)             // 32768 rows
#define TSZ   (BH_*S_*DH_)        // 8,388,608 bf16 elems per projected tensor
#define MEANH_ELEMS (BS_*HID_)    // 8,388,608
#define PROBS_OFF   (2*MEANH_ELEMS)

typedef __attribute__((ext_vector_type(8))) short s16x8;
typedef __attribute__((ext_vector_type(4))) short s16x4;
typedef __attribute__((ext_vector_type(4))) float f32x4;

#define MFMA16(acc, a, b) (acc) = __builtin_amdgcn_mfma_f32_16x16x32_bf16((a), (b), (acc), 0, 0, 0)

static __device__ __forceinline__ short f2bf(float f) {
    union { float f; unsigned u; } a; a.f = f;
    unsigned r = a.u + 0x7fffu + ((a.u >> 16) & 1u);   // RNE
    return (short)(r >> 16);
}
static __device__ __forceinline__ float b2f(short s) {
    union { unsigned u; float f; } a; a.u = ((unsigned)(unsigned short)s) << 16;
    return a.f;
}

// ---------------- kernel 1: weights f32 -> bf16 ----------------
struct WSrc { const float* w[8]; };

__global__ __launch_bounds__(256) void k_w2bf(WSrc src, short* wbf) {
    int t  = blockIdx.x * 256 + threadIdx.x;   // 131072 threads, 4 elems each
    int e4 = t * 4;
    int mi = e4 >> 16; int off = e4 & 65535;
    f32x4 v = *(const f32x4*)(src.w[mi] + off);
    s16x4 o;
    o[0] = f2bf(v[0]); o[1] = f2bf(v[1]); o[2] = f2bf(v[2]); o[3] = f2bf(v[3]);
    *(s16x4*)(wbf + mi * 65536 + off) = o;
}

// ---------------- kernel 1b: inputs f32 -> bf16 (once, instead of 12x in k_proj) ----------------
__global__ __launch_bounds__(256) void k_x2bf(const float* xm, const float* xc,
                                              short* outm, short* outc) {
    const float* src = blockIdx.y ? xc : xm;
    short* dst = blockIdx.y ? outc : outm;
    size_t e = ((size_t)blockIdx.x * 256 + threadIdx.x) * 8;
    f32x4 v0 = *(const f32x4*)(src + e);
    f32x4 v1 = *(const f32x4*)(src + e + 4);
    s16x8 o;
    o[0] = f2bf(v0[0]); o[1] = f2bf(v0[1]); o[2] = f2bf(v0[2]); o[3] = f2bf(v0[3]);
    o[4] = f2bf(v1[0]); o[5] = f2bf(v1[1]); o[6] = f2bf(v1[2]); o[7] = f2bf(v1[3]);
    *(s16x8*)(dst + e) = o;
}

// ---------------- kernel 2: QKV projections, 3 projections fused per block ----------------
// zg=0: mean input -> {mq, mk, mv(->mvT)};  zg=1: cov input -> {sq, sk, cv(->cvT)}
// X staged ONCE per K-step for all 3 projections; 12 MFMA per 2 barriers.
struct BiasP { const float* b[6]; };

__global__ __launch_bounds__(256) void k_proj(const short* xbfM, const short* xbfC,
                                              const short* wbf, BiasP bp,
                                              short* mq, short* mk, short* sq, short* sk,
                                              short* mvT, short* cvT) {
    const int zg = blockIdx.z;            // 0: mean triple, 1: cov triple
    const short* X = zg ? xbfC : xbfM;
    const short* W0 = wbf + zg * 3 * 65536;
    const int m0 = blockIdx.x * 64, n0 = blockIdx.y * 64;
    const int tid = threadIdx.x, wv = tid >> 6, l = tid & 63;

    __shared__ __align__(16) short x_l[64][40];      // 32 used + pad
    __shared__ __align__(16) short w_l[3][64][40];
    __shared__ __align__(16) short t_l[64][65];      // transpose staging (odd stride)

    f32x4 zero4 = {0.f, 0.f, 0.f, 0.f};
    f32x4 acc[3][4];
    #pragma unroll
    for (int p = 0; p < 3; p++)
        #pragma unroll
        for (int nt = 0; nt < 4; nt++) acc[p][nt] = zero4;

    const int srow = tid >> 2, sci = (tid & 3) * 8;
    for (int kk = 0; kk < 8; kk++) {
        const int k0 = kk * 32;
        *(s16x8*)&x_l[srow][sci] = *(const s16x8*)(X + (size_t)(m0 + srow) * HID_ + k0 + sci);
        #pragma unroll
        for (int p = 0; p < 3; p++)
            *(s16x8*)&w_l[p][srow][sci] = *(const s16x8*)(W0 + p * 65536 + (n0 + srow) * HID_ + k0 + sci);
        __syncthreads();
        s16x8 a = *(const s16x8*)&x_l[wv * 16 + (l & 15)][8 * (l >> 4)];
        #pragma unroll
        for (int p = 0; p < 3; p++) {
            #pragma unroll
            for (int nt = 0; nt < 4; nt++) {
                s16x8 b = *(const s16x8*)&w_l[p][nt * 16 + (l & 15)][8 * (l >> 4)];
                MFMA16(acc[p][nt], a, b);
            }
        }
        __syncthreads();
    }

    const int bb = m0 >> 9;          // batch
    const int s0 = m0 & 511;         // seq base
    const int h  = blockIdx.y;       // head (BN=64 == DH)

    #pragma unroll
    for (int p = 0; p < 3; p++) {
        const float* bias = bp.b[zg * 3 + p];
        short* dstd = (p == 0) ? (zg ? sq : mq) : (zg ? sk : mk);   // p<2 direct stores
        #pragma unroll
        for (int nt = 0; nt < 4; nt++) {
            #pragma unroll
            for (int r = 0; r < 4; r++) {
                int ml = wv * 16 + 4 * (l >> 4) + r;
                int ol = nt * 16 + (l & 15);
                float val = acc[p][nt][r] + bias[n0 + ol];
                if (zg == 1) {
                    float e1 = (val > 0.f) ? val + 1.f : __expf(val);
                    val = (p < 2) ? sqrtf(fmaxf(e1, 1e-24f)) : e1;
                }
                short bfv = f2bf(val);
                if (p == 2) t_l[ml][ol] = bfv;
                else        dstd[(((size_t)(bb * NH_ + h) * S_ + (s0 + ml)) * DH_) + ol] = bfv;
            }
        }
    }
    __syncthreads();                 // t_l complete
    {
        short* dst = zg ? cvT : mvT;
        #pragma unroll
        for (int i = 0; i < 2; i++) {
            int g = tid + i * 256; int orow = g >> 3, ci = g & 7;
            s16x8 v;
            #pragma unroll
            for (int j = 0; j < 8; j++) v[j] = t_l[ci * 8 + j][orow];
            *(s16x8*)(dst + ((size_t)(bb * NH_ + h) * DH_ + orow) * S_ + s0 + ci * 8) = v;
        }
    }
}

// ---------------- kernel 3: k row sums (||mk||^2+||sk||^2), vectorized ----------------
__global__ __launch_bounds__(256) void k_rowsum(const short* mk, const short* sk, float* ksum) {
    int row = (blockIdx.x * 256 + threadIdx.x) >> 3;   // 4096 blocks -> 131072 rows
    int c   = (threadIdx.x & 7) * 8;
    s16x8 av = *(const s16x8*)(mk + (size_t)row * 64 + c);
    s16x8 bv = *(const s16x8*)(sk + (size_t)row * 64 + c);
    float s = 0.f;
    #pragma unroll
    for (int j = 0; j < 8; j++) { float a = b2f(av[j]); float b = b2f(bv[j]); s += a * a + b * b; }
    #pragma unroll
    for (int m = 1; m < 8; m <<= 1) s += __shfl_xor(s, m);
    if ((threadIdx.x & 7) == 0) ksum[row] = s;
}

// ---------------- kernel 4: fused Wasserstein attention (v12) ----------------
// Round-0 schedule verbatim; ONLY change: kbuf pad-72 layout replaced by
// [2][2][64][64] with XOR swizzle (byte ^= (row&7)<<4) -- v10-verified,
// halves SQ_LDS_BANK_CONFLICT (8.1M -> ~4M). rsum_l stays in LDS (v10's
// rowsum-through-global-scratch regression is NOT carried over).
// smem union: kbuf 32768B / pT 32768B / ctx_l 8192B.
__global__ __launch_bounds__(256, 4) void k_attn(const short* mq, const short* mk,
                                                 const short* sq, const short* sk,
                                                 const short* mvT, const short* cvT,
                                                 const float* ksum,
                                                 const float* mask, float* probs,
                                                 short* mctx, short* cctx) {
    const int vb = (blockIdx.x & 7) * 512 + (blockIdx.x >> 3);   // XCD grouping
    const int bh = vb >> 4, qb = vb & 15;
    const int b = bh >> 2, h = bh & 3;
    const int q0 = qb * 32;
    const int tid = threadIdx.x, w = tid >> 6, l = tid & 63;
    const int mt = w & 1, kq = w >> 1;        // q-tile (16 rows), k-half (256 k)
    const int lg = l >> 4, lr = l & 15;

    __shared__ __align__(16) char smem[32768];
    __shared__ float rsum_l[32][2];

#define KB(buf, t, row, col) ((short*)(smem + (((buf) * 2 + (t)) * 64 + (row)) * 128 + ((((col) * 2) ^ (((row) & 7) << 4)))))
#define SWZ(row) ((((row) & 7) << 4) ^ (((row) & 8) << 3))

    const short* mkB = mk + (size_t)bh * (S_ * DH_);
    const short* skB = sk + (size_t)bh * (S_ * DH_);
    const float* ksB = ksum + bh * S_;
    const float* maskR = mask + (size_t)b * (S_ * S_) + (size_t)(q0 + mt * 16 + lr) * S_;

    // Q B-frags (held in regs all of QK); per-lane q = q0 + mt*16 + lr
    const short* mqR = mq + (size_t)bh * (S_ * DH_) + (size_t)(q0 + mt * 16 + lr) * DH_;
    const short* sqR = sq + (size_t)bh * (S_ * DH_) + (size_t)(q0 + mt * 16 + lr) * DH_;
    s16x8 qm0 = *(const s16x8*)(mqR + 8 * lg);
    s16x8 qm1 = *(const s16x8*)(mqR + 32 + 8 * lg);
    s16x8 qv0 = *(const s16x8*)(sqR + 8 * lg);
    s16x8 qv1 = *(const s16x8*)(sqR + 32 + 8 * lg);
    float qsv = 0.f;
    #pragma unroll
    for (int j = 0; j < 8; j++) {
        float a0 = b2f(qm0[j]), a1 = b2f(qm1[j]);
        float c0 = b2f(qv0[j]), c1 = b2f(qv1[j]);
        qsv += a0 * a0 + a1 * a1 + c0 * c0 + c1 * c1;
    }
    qsv += __shfl_xor(qsv, 16); qsv += __shfl_xor(qsv, 32);

    // K staging (issue-early / write-late, double-buffered, 1 barrier per tile)
    const int srow = tid >> 3, sci = (tid & 7) * 8;
    s16x8 Rm[2], Rs[2];
    auto ldK = [&](int kt) {
        #pragma unroll
        for (int i = 0; i < 2; i++) {
            int row = kt * 64 + srow + i * 32;
            Rm[i] = *(const s16x8*)(mkB + row * 64 + sci);
            Rs[i] = *(const s16x8*)(skB + row * 64 + sci);
        }
    };
    auto wrK = [&](int buf) {
        #pragma unroll
        for (int i = 0; i < 2; i++) {
            *(s16x8*)KB(buf, 0, srow + i * 32, sci) = Rm[i];
            *(s16x8*)KB(buf, 1, srow + i * 32, sci) = Rs[i];
        }
    };

    ldK(0); wrK(0); ldK(1);
    __syncthreads();

    // ---- QK phase ----
    s16x4 pb[8][2];
    float rs = 0.f;
    #pragma unroll
    for (int kt = 0; kt < 8; kt++) {
        const int cb = kt & 1;
        #pragma unroll
        for (int nn = 0; nn < 2; nn++) {
            const int krl = kq * 32 + nn * 16 + lr;
            s16x8 am0 = *(const s16x8*)KB(cb, 0, krl, 8 * lg);
            s16x8 am1 = *(const s16x8*)KB(cb, 0, krl, 32 + 8 * lg);
            s16x8 as0 = *(const s16x8*)KB(cb, 1, krl, 8 * lg);
            s16x8 as1 = *(const s16x8*)KB(cb, 1, krl, 32 + 8 * lg);
            const int kbase = kt * 64 + kq * 32 + nn * 16 + 4 * lg;
            f32x4 kv  = *(const f32x4*)(ksB + kbase);
            f32x4 mkv = *(const f32x4*)(maskR + kbase);
            f32x4 acc = {0.f, 0.f, 0.f, 0.f};
            MFMA16(acc, am0, qm0); MFMA16(acc, am1, qm1);
            MFMA16(acc, as0, qv0); MFMA16(acc, as1, qv1);
            s16x4 pv;
            #pragma unroll
            for (int r = 0; r < 4; r++) {
                float dist = qsv + kv[r] - 2.f * acc[r];
                float t = __expf(-dist) * 0.125f;
                float p = __expf(t + mkv[r]);        // scores tiny: no max-subtract
                rs += p;
                pv[r] = f2bf(p);
            }
            pb[kt][nn] = pv;
        }
        if (kt < 7) {
            wrK(cb ^ 1);                  // writes other buffer: no conflict with readers
            if (kt < 6) ldK(kt + 2);      // loads stay in flight across the barrier
        }
        __syncthreads();                  // kt=7: kbuf-dead fence before pT staging
    }

    // row sums (k is the register dim: reduce lg quarters) and P -> pT
    rs += __shfl_xor(rs, 16); rs += __shfl_xor(rs, 32);
    if (l < 16) rsum_l[mt * 16 + l][kq] = rs;
    {
        const int wrow = mt * 16 + lr;
        const int sw = SWZ(wrow);
        #pragma unroll
        for (int kt = 0; kt < 8; kt++)
            #pragma unroll
            for (int nn = 0; nn < 2; nn++) {
                int colb = (kt * 64 + kq * 32 + nn * 16 + 4 * lg) * 2;
                *(s16x4*)(smem + wrow * 1024 + (colb ^ sw)) = pb[kt][nn];
            }
    }
    // PV V prefetch (global), issued before the barrier
    const short* mvR = mvT + (size_t)bh * (DH_ * S_) + (size_t)(w * 16 + lr) * S_;
    const short* cvR = cvT + (size_t)bh * (DH_ * S_) + (size_t)(w * 16 + lr) * S_;
    s16x8 Vbuf[2][4];
    auto LDV = [&](int kt, s16x8* V) {
        V[0] = *(const s16x8*)(mvR + kt * 64 + 8 * lg);
        V[1] = *(const s16x8*)(mvR + kt * 64 + 32 + 8 * lg);
        V[2] = *(const s16x8*)(cvR + kt * 64 + 8 * lg);
        V[3] = *(const s16x8*)(cvR + kt * 64 + 32 + 8 * lg);
    };
    LDV(0, Vbuf[0]);
    __syncthreads();

    // ---- probs output (coalesced 256B segments per 8-lane group) ----
    {
        const int prow = tid >> 3, pc = tid & 7;
        const int sw = SWZ(prow);
        const float rvp = 1.f / (rsum_l[prow][0] + rsum_l[prow][1]);
        float* probsB = probs + (size_t)bh * (S_ * S_) + (size_t)(q0 + prow) * S_;
        #pragma unroll
        for (int i = 0; i < 8; i++) {
            int k0 = pc * 8 + i * 64;
            s16x8 pv = *(const s16x8*)(smem + prow * 1024 + ((k0 * 2) ^ sw));
            f32x4 o0, o1;
            #pragma unroll
            for (int j = 0; j < 4; j++) { o0[j] = b2f(pv[j]) * rvp; o1[j] = b2f(pv[4 + j]) * rvp; }
            *(f32x4*)(probsB + k0) = o0;
            *(f32x4*)(probsB + k0 + 4) = o1;
        }
    }

    // ---- PV: ctx^T[d][q] = mfma(A=V^T, B=P^T); P^2 squared from read frag ----
    float rvq[2];
    #pragma unroll
    for (int qt = 0; qt < 2; qt++)
        rvq[qt] = 1.f / (rsum_l[qt * 16 + lr][0] + rsum_l[qt * 16 + lr][1]);

    f32x4 zero4 = {0.f, 0.f, 0.f, 0.f};
    f32x4 om[2] = {zero4, zero4};
    f32x4 oc[2] = {zero4, zero4};
    #pragma unroll
    for (int kt = 0; kt < 8; kt++) {
        const int cur = kt & 1;
        if (kt < 7) LDV(kt + 1, Vbuf[cur ^ 1]);
        #pragma unroll
        for (int qt = 0; qt < 2; qt++) {
            const int brow = qt * 16 + lr;
            const int sw = SWZ(brow);
            #pragma unroll
            for (int koff = 0; koff < 2; koff++) {
                int byteoff = kt * 128 + koff * 64 + 16 * lg;
                s16x8 bp = *(const s16x8*)(smem + brow * 1024 + (byteoff ^ sw));
                s16x8 bp2;
                #pragma unroll
                for (int j = 0; j < 8; j++) { float f = b2f(bp[j]); bp2[j] = f2bf(f * f); }
                MFMA16(om[qt], Vbuf[cur][koff], bp);
                MFMA16(oc[qt], Vbuf[cur][2 + koff], bp2);
            }
        }
    }

    // ---- ctx epilogue: stage through LDS for 128B-coalesced stores ----
    __syncthreads();                     // pT dead
    char* cm = smem;                     // [32][64] bf16, 128B rows, swizzled
    char* cc = smem + 4096;
    #pragma unroll
    for (int qt = 0; qt < 2; qt++) {
        const int row = qt * 16 + lr;
        const int sw = SWZ(row);
        const float rv = rvq[qt];
        s16x4 vm, vc;
        #pragma unroll
        for (int r = 0; r < 4; r++) {
            vm[r] = f2bf(om[qt][r] * rv);
            vc[r] = f2bf(oc[qt][r] * rv * rv);
        }
        int colb = (w * 16 + 4 * lg) * 2;
        *(s16x4*)(cm + row * 128 + (colb ^ sw)) = vm;
        *(s16x4*)(cc + row * 128 + (colb ^ sw)) = vc;
    }
    __syncthreads();
    {
        const int row = tid >> 3, pc = tid & 7;
        const int sw = SWZ(row);
        s16x8 vm = *(const s16x8*)(cm + row * 128 + ((pc * 16) ^ sw));
        s16x8 vc = *(const s16x8*)(cc + row * 128 + ((pc * 16) ^ sw));
        size_t base = ((size_t)(b * S_ + q0 + row)) * HID_ + h * DH_ + pc * 8;
        *(s16x8*)(mctx + base) = vm;
        *(s16x8*)(cctx + base) = vc;
    }
#undef KB
#undef SWZ
}

// ---------------- kernel 5: output dense + residual + LayerNorm ----------------
__global__ __launch_bounds__(256) void k_final(const short* mctx, const short* cctx,
                                               const short* wbf,
                                               const float* bmd, const float* bcd,
                                               const float* Xmean, const float* Xcov,
                                               const float* lnw, const float* lnb,
                                               float* outbase) {
    const int which = blockIdx.y;
    const short* C = which ? cctx : mctx;
    const short* W = wbf + (6 + which) * 65536;
    const float* bias = which ? bcd : bmd;
    const float* X = which ? Xcov : Xmean;
    float* out = outbase + (size_t)which * MEANH_ELEMS;

    const int m0 = blockIdx.x * 32;
    const int tid = threadIdx.x, wv = tid >> 6, l = tid & 63;

    __shared__ __align__(16) short c_l[32][40];
    __shared__ __align__(16) short w_l[256][40];
    __shared__ float h_l[32][256];

    f32x4 zero4 = {0.f, 0.f, 0.f, 0.f};
    f32x4 acc[2][4];
    #pragma unroll
    for (int mtI = 0; mtI < 2; mtI++)
        #pragma unroll
        for (int nt = 0; nt < 4; nt++) acc[mtI][nt] = zero4;

    for (int kk = 0; kk < 8; kk++) {
        const int k0 = kk * 32;
        if (tid < 128) {
            int row = tid >> 2, ci = tid & 3;
            *(s16x8*)&c_l[row][ci * 8] = *(const s16x8*)(C + (size_t)(m0 + row) * HID_ + k0 + ci * 8);
        }
        #pragma unroll
        for (int i = 0; i < 4; i++) {
            int g = tid + i * 256; int o = g >> 2, ci = g & 3;
            *(s16x8*)&w_l[o][ci * 8] = *(const s16x8*)(W + o * HID_ + k0 + ci * 8);
        }
        __syncthreads();
        s16x8 a[2];
        #pragma unroll
        for (int mtI = 0; mtI < 2; mtI++)
            a[mtI] = *(const s16x8*)&c_l[mtI * 16 + (l & 15)][8 * (l >> 4)];
        #pragma unroll
        for (int nt = 0; nt < 4; nt++) {
            s16x8 bfr = *(const s16x8*)&w_l[wv * 64 + nt * 16 + (l & 15)][8 * (l >> 4)];
            MFMA16(acc[0][nt], a[0], bfr);
            MFMA16(acc[1][nt], a[1], bfr);
        }
        __syncthreads();
    }
    #pragma unroll
    for (int mtI = 0; mtI < 2; mtI++) {
        #pragma unroll
        for (int nt = 0; nt < 4; nt++) {
            #pragma unroll
            for (int r = 0; r < 4; r++) {
                int ml = mtI * 16 + 4 * (l >> 4) + r;
                int o = wv * 64 + nt * 16 + (l & 15);
                h_l[ml][o] = acc[mtI][nt][r] + bias[o] + X[(size_t)(m0 + ml) * HID_ + o];
            }
        }
    }
    __syncthreads();
    // LayerNorm: each wave owns 8 rows
    #pragma unroll
    for (int i = 0; i < 8; i++) {
        int row = wv * 8 + i;
        float s = 0.f;
        #pragma unroll
        for (int c = 0; c < 4; c++) s += h_l[row][l + c * 64];
        #pragma unroll
        for (int m = 1; m < 64; m <<= 1) s += __shfl_xor(s, m);
        float u = s * (1.f / 256.f);
        float s2 = 0.f;
        #pragma unroll
        for (int c = 0; c < 4; c++) { float d = h_l[row][l + c * 64] - u; s2 += d * d; }
        #pragma unroll
        for (int m = 1; m < 64; m <<= 1) s2 += __shfl_xor(s2, m);
        float rstd = rsqrtf(s2 * (1.f / 256.f) + 1e-12f);
        #pragma unroll
        for (int c = 0; c < 4; c++) {
            int o = l + c * 64;
            out[(size_t)(m0 + row) * HID_ + o] = lnw[o] * ((h_l[row][o] - u) * rstd) + lnb[o];
        }
    }
}

// ---------------- host ----------------
extern "C" void kernel_launch(void* const* d_in, const int* in_sizes, int n_in,
                              void* d_out, int out_size, void* d_ws, size_t ws_size,
                              hipStream_t stream) {
    const float* x_mean = (const float*)d_in[0];
    const float* x_cov  = (const float*)d_in[1];
    const float* mask   = (const float*)d_in[2];
    // weight order in wbf: Wmq Wmk Wmv Wcq Wck Wcv Wmd Wcd
    WSrc src;
    src.w[0] = (const float*)d_in[3];  src.w[1] = (const float*)d_in[5];
    src.w[2] = (const float*)d_in[7];  src.w[3] = (const float*)d_in[9];
    src.w[4] = (const float*)d_in[11]; src.w[5] = (const float*)d_in[13];
    src.w[6] = (const float*)d_in[15]; src.w[7] = (const float*)d_in[17];
    BiasP bp;
    bp.b[0] = (const float*)d_in[4];  bp.b[1] = (const float*)d_in[6];
    bp.b[2] = (const float*)d_in[8];  bp.b[3] = (const float*)d_in[10];
    bp.b[4] = (const float*)d_in[12]; bp.b[5] = (const float*)d_in[14];
    const float* bmd = (const float*)d_in[16];
    const float* bcd = (const float*)d_in[18];
    const float* lnw = (const float*)d_in[19];
    const float* lnb = (const float*)d_in[20];
    float* out = (float*)d_out;

    char* wsb = (char*)d_ws;
    short* wbf = (short*)wsb;                       // 8*65536*2 = 1 MiB
    short* mq  = (short*)(wsb + (1 << 20));
    short* mk  = mq  + TSZ;
    short* sq  = mk  + TSZ;
    short* sk  = sq  + TSZ;
    short* mvT = sk  + TSZ;
    short* cvT = mvT + TSZ;
    float* ksum = (float*)(cvT + TSZ);              // 131072 f32
    short* mctx = (short*)(ksum + (BH_ * S_));
    short* cctx = mctx + TSZ;

    float* probs = out + PROBS_OFF;

    // xbf aliases mctx/cctx: written by k_x2bf, read by k_proj, dead before
    // k_attn writes mctx/cctx (strict stream ordering).
    short* xbfM = mctx;
    short* xbfC = cctx;

    hipLaunchKernelGGL(k_w2bf, dim3(512), dim3(256), 0, stream, src, wbf);
    hipLaunchKernelGGL(k_x2bf, dim3(MEANH_ELEMS / (256 * 8), 2), dim3(256), 0, stream,
                       x_mean, x_cov, xbfM, xbfC);
    hipLaunchKernelGGL(k_proj, dim3(512, 4, 2), dim3(256), 0, stream,
                       xbfM, xbfC, wbf, bp, mq, mk, sq, sk, mvT, cvT);
    hipLaunchKernelGGL(k_rowsum, dim3(4096), dim3(256), 0, stream, mk, sk, ksum);
    hipLaunchKernelGGL(k_attn, dim3(BH_ * 16), dim3(256), 0, stream,
                       mq, mk, sq, sk, mvT, cvT, ksum, mask, probs, mctx, cctx);
    hipLaunchKernelGGL(k_final, dim3(BS_ / 32, 2), dim3(256), 0, stream,
                       mctx, cctx, wbf, bmd, bcd, x_mean, x_cov, lnw, lnb, out);
}

// Round 12
// 352.418 us; speedup vs baseline: 1.0309x; 1.0309x over previous
//
#include <hip/hip_runtime.h>
#include <math.h>

// ---------------- problem constants ----------------
#define B_    64
#define S_    512
#define HID_  256
#define NH_   4
#define DH_   64
#define BH_   (B_*NH_)            // 256 head-batches
#define BS_   (B_*S_)             // 32768 rows
#define TSZ   (BH_*S_*DH_)        // 8,388,608 bf16 elems per projected tensor
#define MEANH_ELEMS (BS_*HID_)    // 8,388,608
#define PROBS_OFF   (2*MEANH_ELEMS)

typedef __attribute__((ext_vector_type(8))) short s16x8;
typedef __attribute__((ext_vector_type(4))) short s16x4;
typedef __attribute__((ext_vector_type(4))) float f32x4;

#define MFMA16(acc, a, b) (acc) = __builtin_amdgcn_mfma_f32_16x16x32_bf16((a), (b), (acc), 0, 0, 0)

static __device__ __forceinline__ short f2bf(float f) {
    union { float f; unsigned u; } a; a.f = f;
    unsigned r = a.u + 0x7fffu + ((a.u >> 16) & 1u);   // RNE
    return (short)(r >> 16);
}
static __device__ __forceinline__ float b2f(short s) {
    union { unsigned u; float f; } a; a.u = ((unsigned)(unsigned short)s) << 16;
    return a.f;
}

// ---------------- kernel 1: weights f32 -> bf16 ----------------
struct WSrc { const float* w[8]; };

__global__ __launch_bounds__(256) void k_w2bf(WSrc src, short* wbf) {
    int t  = blockIdx.x * 256 + threadIdx.x;   // 131072 threads, 4 elems each
    int e4 = t * 4;
    int mi = e4 >> 16; int off = e4 & 65535;
    f32x4 v = *(const f32x4*)(src.w[mi] + off);
    s16x4 o;
    o[0] = f2bf(v[0]); o[1] = f2bf(v[1]); o[2] = f2bf(v[2]); o[3] = f2bf(v[3]);
    *(s16x4*)(wbf + mi * 65536 + off) = o;
}

// ---------------- kernel 1b: inputs f32 -> bf16 (once, instead of 12x in k_proj) ----------------
__global__ __launch_bounds__(256) void k_x2bf(const float* xm, const float* xc,
                                              short* outm, short* outc) {
    const float* src = blockIdx.y ? xc : xm;
    short* dst = blockIdx.y ? outc : outm;
    size_t e = ((size_t)blockIdx.x * 256 + threadIdx.x) * 8;
    f32x4 v0 = *(const f32x4*)(src + e);
    f32x4 v1 = *(const f32x4*)(src + e + 4);
    s16x8 o;
    o[0] = f2bf(v0[0]); o[1] = f2bf(v0[1]); o[2] = f2bf(v0[2]); o[3] = f2bf(v0[3]);
    o[4] = f2bf(v1[0]); o[5] = f2bf(v1[1]); o[6] = f2bf(v1[2]); o[7] = f2bf(v1[3]);
    *(s16x8*)(dst + e) = o;
}

// ---------------- kernel 2: QKV projections, 3 projections fused per block ----------------
// zg=0: mean input -> {mq, mk, mv(->mvT)};  zg=1: cov input -> {sq, sk, cv(->cvT)}
// X staged ONCE per K-step for all 3 projections; 12 MFMA per 2 barriers.
struct BiasP { const float* b[6]; };

__global__ __launch_bounds__(256) void k_proj(const short* xbfM, const short* xbfC,
                                              const short* wbf, BiasP bp,
                                              short* mq, short* mk, short* sq, short* sk,
                                              short* mvT, short* cvT) {
    const int zg = blockIdx.z;            // 0: mean triple, 1: cov triple
    const short* X = zg ? xbfC : xbfM;
    const short* W0 = wbf + zg * 3 * 65536;
    const int m0 = blockIdx.x * 64, n0 = blockIdx.y * 64;
    const int tid = threadIdx.x, wv = tid >> 6, l = tid & 63;

    __shared__ __align__(16) short x_l[64][40];      // 32 used + pad
    __shared__ __align__(16) short w_l[3][64][40];
    __shared__ __align__(16) short t_l[64][65];      // transpose staging (odd stride)

    f32x4 zero4 = {0.f, 0.f, 0.f, 0.f};
    f32x4 acc[3][4];
    #pragma unroll
    for (int p = 0; p < 3; p++)
        #pragma unroll
        for (int nt = 0; nt < 4; nt++) acc[p][nt] = zero4;

    const int srow = tid >> 2, sci = (tid & 3) * 8;
    for (int kk = 0; kk < 8; kk++) {
        const int k0 = kk * 32;
        *(s16x8*)&x_l[srow][sci] = *(const s16x8*)(X + (size_t)(m0 + srow) * HID_ + k0 + sci);
        #pragma unroll
        for (int p = 0; p < 3; p++)
            *(s16x8*)&w_l[p][srow][sci] = *(const s16x8*)(W0 + p * 65536 + (n0 + srow) * HID_ + k0 + sci);
        __syncthreads();
        s16x8 a = *(const s16x8*)&x_l[wv * 16 + (l & 15)][8 * (l >> 4)];
        #pragma unroll
        for (int p = 0; p < 3; p++) {
            #pragma unroll
            for (int nt = 0; nt < 4; nt++) {
                s16x8 b = *(const s16x8*)&w_l[p][nt * 16 + (l & 15)][8 * (l >> 4)];
                MFMA16(acc[p][nt], a, b);
            }
        }
        __syncthreads();
    }

    const int bb = m0 >> 9;          // batch
    const int s0 = m0 & 511;         // seq base
    const int h  = blockIdx.y;       // head (BN=64 == DH)

    #pragma unroll
    for (int p = 0; p < 3; p++) {
        const float* bias = bp.b[zg * 3 + p];
        short* dstd = (p == 0) ? (zg ? sq : mq) : (zg ? sk : mk);   // p<2 direct stores
        #pragma unroll
        for (int nt = 0; nt < 4; nt++) {
            #pragma unroll
            for (int r = 0; r < 4; r++) {
                int ml = wv * 16 + 4 * (l >> 4) + r;
                int ol = nt * 16 + (l & 15);
                float val = acc[p][nt][r] + bias[n0 + ol];
                if (zg == 1) {
                    float e1 = (val > 0.f) ? val + 1.f : __expf(val);
                    val = (p < 2) ? sqrtf(fmaxf(e1, 1e-24f)) : e1;
                }
                short bfv = f2bf(val);
                if (p == 2) t_l[ml][ol] = bfv;
                else        dstd[(((size_t)(bb * NH_ + h) * S_ + (s0 + ml)) * DH_) + ol] = bfv;
            }
        }
    }
    __syncthreads();                 // t_l complete
    {
        short* dst = zg ? cvT : mvT;
        #pragma unroll
        for (int i = 0; i < 2; i++) {
            int g = tid + i * 256; int orow = g >> 3, ci = g & 7;
            s16x8 v;
            #pragma unroll
            for (int j = 0; j < 8; j++) v[j] = t_l[ci * 8 + j][orow];
            *(s16x8*)(dst + ((size_t)(bb * NH_ + h) * DH_ + orow) * S_ + s0 + ci * 8) = v;
        }
    }
}

// ---------------- kernel 3: k row sums (||mk||^2+||sk||^2), vectorized ----------------
__global__ __launch_bounds__(256) void k_rowsum(const short* mk, const short* sk, float* ksum) {
    int row = (blockIdx.x * 256 + threadIdx.x) >> 3;   // 4096 blocks -> 131072 rows
    int c   = (threadIdx.x & 7) * 8;
    s16x8 av = *(const s16x8*)(mk + (size_t)row * 64 + c);
    s16x8 bv = *(const s16x8*)(sk + (size_t)row * 64 + c);
    float s = 0.f;
    #pragma unroll
    for (int j = 0; j < 8; j++) { float a = b2f(av[j]); float b = b2f(bv[j]); s += a * a + b * b; }
    #pragma unroll
    for (int m = 1; m < 8; m <<= 1) s += __shfl_xor(s, m);
    if ((threadIdx.x & 7) == 0) ksum[row] = s;
}

// ---------------- kernel 4: fused Wasserstein attention (Round-0 verbatim) ----------------
// Measured best: 193 us, FETCH 88MB, WRITE 299MB, occ 42%, VGPR 64.
// Session evidence: 8 restructures regressed (latency-tuned local optimum);
// occupancy capped at 4 blocks/CU regardless of LDS<=37KB (v10); bank
// conflicts hidden (v12: halved conflicts, +5% time). Keep verbatim.
__global__ __launch_bounds__(256, 4) void k_attn(const short* mq, const short* mk,
                                                 const short* sq, const short* sk,
                                                 const short* mvT, const short* cvT,
                                                 const float* ksum,
                                                 const float* mask, float* probs,
                                                 short* mctx, short* cctx) {
    const int vb = (blockIdx.x & 7) * 512 + (blockIdx.x >> 3);   // XCD grouping
    const int bh = vb >> 4, qb = vb & 15;
    const int b = bh >> 2, h = bh & 3;
    const int q0 = qb * 32;
    const int tid = threadIdx.x, w = tid >> 6, l = tid & 63;
    const int mt = w & 1, kq = w >> 1;        // q-tile (16 rows), k-half (256 k)
    const int lg = l >> 4, lr = l & 15;

    // union: kbuf[2][2][64][72] (36864B, QK phase) / pT[32][512] swizzled
    // (32768B, PV phase) / ctx_l (8192B, epilogue)
    __shared__ __align__(16) char smem[36864];
    __shared__ float rsum_l[32][2];
    short* s16p = (short*)smem;

#define KB(buf, t, row, col) (s16p + (((buf) * 2 + (t)) * 64 + (row)) * 72 + (col))
#define SWZ(row) ((((row) & 7) << 4) ^ (((row) & 8) << 3))

    const short* mkB = mk + (size_t)bh * (S_ * DH_);
    const short* skB = sk + (size_t)bh * (S_ * DH_);
    const float* ksB = ksum + bh * S_;
    const float* maskR = mask + (size_t)b * (S_ * S_) + (size_t)(q0 + mt * 16 + lr) * S_;

    // Q B-frags (held in regs all of QK); per-lane q = q0 + mt*16 + lr
    const short* mqR = mq + (size_t)bh * (S_ * DH_) + (size_t)(q0 + mt * 16 + lr) * DH_;
    const short* sqR = sq + (size_t)bh * (S_ * DH_) + (size_t)(q0 + mt * 16 + lr) * DH_;
    s16x8 qm0 = *(const s16x8*)(mqR + 8 * lg);
    s16x8 qm1 = *(const s16x8*)(mqR + 32 + 8 * lg);
    s16x8 qv0 = *(const s16x8*)(sqR + 8 * lg);
    s16x8 qv1 = *(const s16x8*)(sqR + 32 + 8 * lg);
    float qsv = 0.f;
    #pragma unroll
    for (int j = 0; j < 8; j++) {
        float a0 = b2f(qm0[j]), a1 = b2f(qm1[j]);
        float c0 = b2f(qv0[j]), c1 = b2f(qv1[j]);
        qsv += a0 * a0 + a1 * a1 + c0 * c0 + c1 * c1;
    }
    qsv += __shfl_xor(qsv, 16); qsv += __shfl_xor(qsv, 32);

    // K staging (issue-early / write-late, double-buffered, 1 barrier per tile)
    const int srow = tid >> 3, sci = (tid & 7) * 8;
    s16x8 Rm[2], Rs[2];
    auto ldK = [&](int kt) {
        #pragma unroll
        for (int i = 0; i < 2; i++) {
            int row = kt * 64 + srow + i * 32;
            Rm[i] = *(const s16x8*)(mkB + row * 64 + sci);
            Rs[i] = *(const s16x8*)(skB + row * 64 + sci);
        }
    };
    auto wrK = [&](int buf) {
        #pragma unroll
        for (int i = 0; i < 2; i++) {
            *(s16x8*)KB(buf, 0, srow + i * 32, sci) = Rm[i];
            *(s16x8*)KB(buf, 1, srow + i * 32, sci) = Rs[i];
        }
    };

    ldK(0); wrK(0); ldK(1);
    __syncthreads();

    // ---- QK phase ----
    s16x4 pb[8][2];
    float rs = 0.f;
    #pragma unroll
    for (int kt = 0; kt < 8; kt++) {
        const int cb = kt & 1;
        #pragma unroll
        for (int nn = 0; nn < 2; nn++) {
            const int krl = kq * 32 + nn * 16 + lr;
            s16x8 am0 = *(const s16x8*)KB(cb, 0, krl, 8 * lg);
            s16x8 am1 = *(const s16x8*)KB(cb, 0, krl, 32 + 8 * lg);
            s16x8 as0 = *(const s16x8*)KB(cb, 1, krl, 8 * lg);
            s16x8 as1 = *(const s16x8*)KB(cb, 1, krl, 32 + 8 * lg);
            const int kbase = kt * 64 + kq * 32 + nn * 16 + 4 * lg;
            f32x4 kv  = *(const f32x4*)(ksB + kbase);
            f32x4 mkv = *(const f32x4*)(maskR + kbase);
            f32x4 acc = {0.f, 0.f, 0.f, 0.f};
            MFMA16(acc, am0, qm0); MFMA16(acc, am1, qm1);
            MFMA16(acc, as0, qv0); MFMA16(acc, as1, qv1);
            s16x4 pv;
            #pragma unroll
            for (int r = 0; r < 4; r++) {
                float dist = qsv + kv[r] - 2.f * acc[r];
                float t = __expf(-dist) * 0.125f;
                float p = __expf(t + mkv[r]);        // scores tiny: no max-subtract
                rs += p;
                pv[r] = f2bf(p);
            }
            pb[kt][nn] = pv;
        }
        if (kt < 7) {
            wrK(cb ^ 1);                  // writes other buffer: no conflict with readers
            if (kt < 6) ldK(kt + 2);      // loads stay in flight across the barrier
        }
        __syncthreads();
    }

    // row sums (k is the register dim: reduce lg quarters) and P -> pT
    rs += __shfl_xor(rs, 16); rs += __shfl_xor(rs, 32);
    if (l < 16) rsum_l[mt * 16 + l][kq] = rs;
    {
        const int wrow = mt * 16 + lr;
        const int sw = SWZ(wrow);
        #pragma unroll
        for (int kt = 0; kt < 8; kt++)
            #pragma unroll
            for (int nn = 0; nn < 2; nn++) {
                int colb = (kt * 64 + kq * 32 + nn * 16 + 4 * lg) * 2;
                *(s16x4*)(smem + wrow * 1024 + (colb ^ sw)) = pb[kt][nn];
            }
    }
    // PV V prefetch (global), issued before the barrier
    const short* mvR = mvT + (size_t)bh * (DH_ * S_) + (size_t)(w * 16 + lr) * S_;
    const short* cvR = cvT + (size_t)bh * (DH_ * S_) + (size_t)(w * 16 + lr) * S_;
    s16x8 Vbuf[2][4];
    auto LDV = [&](int kt, s16x8* V) {
        V[0] = *(const s16x8*)(mvR + kt * 64 + 8 * lg);
        V[1] = *(const s16x8*)(mvR + kt * 64 + 32 + 8 * lg);
        V[2] = *(const s16x8*)(cvR + kt * 64 + 8 * lg);
        V[3] = *(const s16x8*)(cvR + kt * 64 + 32 + 8 * lg);
    };
    LDV(0, Vbuf[0]);
    __syncthreads();

    // ---- probs output (coalesced 256B segments per 8-lane group) ----
    {
        const int prow = tid >> 3, pc = tid & 7;
        const int sw = SWZ(prow);
        const float rvp = 1.f / (rsum_l[prow][0] + rsum_l[prow][1]);
        float* probsB = probs + (size_t)bh * (S_ * S_) + (size_t)(q0 + prow) * S_;
        #pragma unroll
        for (int i = 0; i < 8; i++) {
            int k0 = pc * 8 + i * 64;
            s16x8 pv = *(const s16x8*)(smem + prow * 1024 + ((k0 * 2) ^ sw));
            f32x4 o0, o1;
            #pragma unroll
            for (int j = 0; j < 4; j++) { o0[j] = b2f(pv[j]) * rvp; o1[j] = b2f(pv[4 + j]) * rvp; }
            *(f32x4*)(probsB + k0) = o0;
            *(f32x4*)(probsB + k0 + 4) = o1;
        }
    }

    // ---- PV: ctx^T[d][q] = mfma(A=V^T, B=P^T); P^2 squared from read frag ----
    float rvq[2];
    #pragma unroll
    for (int qt = 0; qt < 2; qt++)
        rvq[qt] = 1.f / (rsum_l[qt * 16 + lr][0] + rsum_l[qt * 16 + lr][1]);

    f32x4 zero4 = {0.f, 0.f, 0.f, 0.f};
    f32x4 om[2] = {zero4, zero4};
    f32x4 oc[2] = {zero4, zero4};
    #pragma unroll
    for (int kt = 0; kt < 8; kt++) {
        const int cur = kt & 1;
        if (kt < 7) LDV(kt + 1, Vbuf[cur ^ 1]);
        #pragma unroll
        for (int qt = 0; qt < 2; qt++) {
            const int brow = qt * 16 + lr;
            const int sw = SWZ(brow);
            #pragma unroll
            for (int koff = 0; koff < 2; koff++) {
                int byteoff = kt * 128 + koff * 64 + 16 * lg;
                s16x8 bp = *(const s16x8*)(smem + brow * 1024 + (byteoff ^ sw));
                s16x8 bp2;
                #pragma unroll
                for (int j = 0; j < 8; j++) { float f = b2f(bp[j]); bp2[j] = f2bf(f * f); }
                MFMA16(om[qt], Vbuf[cur][koff], bp);
                MFMA16(oc[qt], Vbuf[cur][2 + koff], bp2);
            }
        }
    }

    // ---- ctx epilogue: stage through LDS for 128B-coalesced stores ----
    __syncthreads();                     // pT dead
    char* cm = smem;                     // [32][64] bf16, 128B rows, swizzled
    char* cc = smem + 4096;
    #pragma unroll
    for (int qt = 0; qt < 2; qt++) {
        const int row = qt * 16 + lr;
        const int sw = SWZ(row);
        const float rv = rvq[qt];
        s16x4 vm, vc;
        #pragma unroll
        for (int r = 0; r < 4; r++) {
            vm[r] = f2bf(om[qt][r] * rv);
            vc[r] = f2bf(oc[qt][r] * rv * rv);
        }
        int colb = (w * 16 + 4 * lg) * 2;
        *(s16x4*)(cm + row * 128 + (colb ^ sw)) = vm;
        *(s16x4*)(cc + row * 128 + (colb ^ sw)) = vc;
    }
    __syncthreads();
    {
        const int row = tid >> 3, pc = tid & 7;
        const int sw = SWZ(row);
        s16x8 vm = *(const s16x8*)(cm + row * 128 + ((pc * 16) ^ sw));
        s16x8 vc = *(const s16x8*)(cc + row * 128 + ((pc * 16) ^ sw));
        size_t base = ((size_t)(b * S_ + q0 + row)) * HID_ + h * DH_ + pc * 8;
        *(s16x8*)(mctx + base) = vm;
        *(s16x8*)(cctx + base) = vc;
    }
#undef KB
#undef SWZ
}

// ---------------- kernel 5: output dense + residual + LayerNorm ----------------
__global__ __launch_bounds__(256) void k_final(const short* mctx, const short* cctx,
                                               const short* wbf,
                                               const float* bmd, const float* bcd,
                                               const float* Xmean, const float* Xcov,
                                               const float* lnw, const float* lnb,
                                               float* outbase) {
    const int which = blockIdx.y;
    const short* C = which ? cctx : mctx;
    const short* W = wbf + (6 + which) * 65536;
    const float* bias = which ? bcd : bmd;
    const float* X = which ? Xcov : Xmean;
    float* out = outbase + (size_t)which * MEANH_ELEMS;

    const int m0 = blockIdx.x * 32;
    const int tid = threadIdx.x, wv = tid >> 6, l = tid & 63;

    __shared__ __align__(16) short c_l[32][40];
    __shared__ __align__(16) short w_l[256][40];
    __shared__ float h_l[32][256];

    f32x4 zero4 = {0.f, 0.f, 0.f, 0.f};
    f32x4 acc[2][4];
    #pragma unroll
    for (int mtI = 0; mtI < 2; mtI++)
        #pragma unroll
        for (int nt = 0; nt < 4; nt++) acc[mtI][nt] = zero4;

    for (int kk = 0; kk < 8; kk++) {
        const int k0 = kk * 32;
        if (tid < 128) {
            int row = tid >> 2, ci = tid & 3;
            *(s16x8*)&c_l[row][ci * 8] = *(const s16x8*)(C + (size_t)(m0 + row) * HID_ + k0 + ci * 8);
        }
        #pragma unroll
        for (int i = 0; i < 4; i++) {
            int g = tid + i * 256; int o = g >> 2, ci = g & 3;
            *(s16x8*)&w_l[o][ci * 8] = *(const s16x8*)(W + o * HID_ + k0 + ci * 8);
        }
        __syncthreads();
        s16x8 a[2];
        #pragma unroll
        for (int mtI = 0; mtI < 2; mtI++)
            a[mtI] = *(const s16x8*)&c_l[mtI * 16 + (l & 15)][8 * (l >> 4)];
        #pragma unroll
        for (int nt = 0; nt < 4; nt++) {
            s16x8 bfr = *(const s16x8*)&w_l[wv * 64 + nt * 16 + (l & 15)][8 * (l >> 4)];
            MFMA16(acc[0][nt], a[0], bfr);
            MFMA16(acc[1][nt], a[1], bfr);
        }
        __syncthreads();
    }
    #pragma unroll
    for (int mtI = 0; mtI < 2; mtI++) {
        #pragma unroll
        for (int nt = 0; nt < 4; nt++) {
            #pragma unroll
            for (int r = 0; r < 4; r++) {
                int ml = mtI * 16 + 4 * (l >> 4) + r;
                int o = wv * 64 + nt * 16 + (l & 15);
                h_l[ml][o] = acc[mtI][nt][r] + bias[o] + X[(size_t)(m0 + ml) * HID_ + o];
            }
        }
    }
    __syncthreads();
    // LayerNorm: each wave owns 8 rows
    #pragma unroll
    for (int i = 0; i < 8; i++) {
        int row = wv * 8 + i;
        float s = 0.f;
        #pragma unroll
        for (int c = 0; c < 4; c++) s += h_l[row][l + c * 64];
        #pragma unroll
        for (int m = 1; m < 64; m <<= 1) s += __shfl_xor(s, m);
        float u = s * (1.f / 256.f);
        float s2 = 0.f;
        #pragma unroll
        for (int c = 0; c < 4; c++) { float d = h_l[row][l + c * 64] - u; s2 += d * d; }
        #pragma unroll
        for (int m = 1; m < 64; m <<= 1) s2 += __shfl_xor(s2, m);
        float rstd = rsqrtf(s2 * (1.f / 256.f) + 1e-12f);
        #pragma unroll
        for (int c = 0; c < 4; c++) {
            int o = l + c * 64;
            out[(size_t)(m0 + row) * HID_ + o] = lnw[o] * ((h_l[row][o] - u) * rstd) + lnb[o];
        }
    }
}

// ---------------- host ----------------
extern "C" void kernel_launch(void* const* d_in, const int* in_sizes, int n_in,
                              void* d_out, int out_size, void* d_ws, size_t ws_size,
                              hipStream_t stream) {
    const float* x_mean = (const float*)d_in[0];
    const float* x_cov  = (const float*)d_in[1];
    const float* mask   = (const float*)d_in[2];
    // weight order in wbf: Wmq Wmk Wmv Wcq Wck Wcv Wmd Wcd
    WSrc src;
    src.w[0] = (const float*)d_in[3];  src.w[1] = (const float*)d_in[5];
    src.w[2] = (const float*)d_in[7];  src.w[3] = (const float*)d_in[9];
    src.w[4] = (const float*)d_in[11]; src.w[5] = (const float*)d_in[13];
    src.w[6] = (const float*)d_in[15]; src.w[7] = (const float*)d_in[17];
    BiasP bp;
    bp.b[0] = (const float*)d_in[4];  bp.b[1] = (const float*)d_in[6];
    bp.b[2] = (const float*)d_in[8];  bp.b[3] = (const float*)d_in[10];
    bp.b[4] = (const float*)d_in[12]; bp.b[5] = (const float*)d_in[14];
    const float* bmd = (const float*)d_in[16];
    const float* bcd = (const float*)d_in[18];
    const float* lnw = (const float*)d_in[19];
    const float* lnb = (const float*)d_in[20];
    float* out = (float*)d_out;

    char* wsb = (char*)d_ws;
    short* wbf = (short*)wsb;                       // 8*65536*2 = 1 MiB
    short* mq  = (short*)(wsb + (1 << 20));
    short* mk  = mq  + TSZ;
    short* sq  = mk  + TSZ;
    short* sk  = sq  + TSZ;
    short* mvT = sk  + TSZ;
    short* cvT = mvT + TSZ;
    float* ksum = (float*)(cvT + TSZ);              // 131072 f32
    short* mctx = (short*)(ksum + (BH_ * S_));
    short* cctx = mctx + TSZ;

    float* probs = out + PROBS_OFF;

    // xbf aliases mctx/cctx: written by k_x2bf, read by k_proj, dead before
    // k_attn writes mctx/cctx (strict stream ordering).
    short* xbfM = mctx;
    short* xbfC = cctx;

    hipLaunchKernelGGL(k_w2bf, dim3(512), dim3(256), 0, stream, src, wbf);
    hipLaunchKernelGGL(k_x2bf, dim3(MEANH_ELEMS / (256 * 8), 2), dim3(256), 0, stream,
                       x_mean, x_cov, xbfM, xbfC);
    hipLaunchKernelGGL(k_proj, dim3(512, 4, 2), dim3(256), 0, stream,
                       xbfM, xbfC, wbf, bp, mq, mk, sq, sk, mvT, cvT);
    hipLaunchKernelGGL(k_rowsum, dim3(4096), dim3(256), 0, stream, mk, sk, ksum);
    hipLaunchKernelGGL(k_attn, dim3(BH_ * 16), dim3(256), 0, stream,
                       mq, mk, sq, sk, mvT, cvT, ksum, mask, probs, mctx, cctx);
    hipLaunchKernelGGL(k_final, dim3(BS_ / 32, 2), dim3(256), 0, stream,
                       mctx, cctx, wbf, bmd, bcd, x_mean, x_cov, lnw, lnb, out);
}